// Round 2
// baseline (247.246 us; speedup 1.0000x reference)
//
#include <hip/hip_runtime.h>

typedef __bf16 bf16x8 __attribute__((ext_vector_type(8)));
typedef float f32x4 __attribute__((ext_vector_type(4)));

static __device__ __forceinline__ f32x4 mfma16(bf16x8 a, bf16x8 b, f32x4 c) {
  return __builtin_amdgcn_mfma_f32_16x16x32_bf16(a, b, c, 0, 0, 0);
}
static __device__ __forceinline__ unsigned cvtpk(float lo, float hi) {
  unsigned r;
  asm("v_cvt_pk_bf16_f32 %0, %1, %2" : "=v"(r) : "v"(lo), "v"(hi));
  return r;
}

// ---- pre-pass 1: K fp32 -> bf16, same [bh][s][d] layout ----
__global__ __launch_bounds__(256)
void cvt_k(const float* __restrict__ K, __bf16* __restrict__ Kb) {
  const int i = (blockIdx.x * 256 + threadIdx.x) * 8;
  float4 a = *(const float4*)(K + i);
  float4 b = *(const float4*)(K + i + 4);
  bf16x8 v;
  v[0] = (__bf16)a.x; v[1] = (__bf16)a.y; v[2] = (__bf16)a.z; v[3] = (__bf16)a.w;
  v[4] = (__bf16)b.x; v[5] = (__bf16)b.y; v[6] = (__bf16)b.z; v[7] = (__bf16)b.w;
  *(bf16x8*)(Kb + i) = v;
}

// ---- pre-pass 2: V [bh][s][64] fp32 -> V^T bf16 [bh][d][2048] ----
__global__ __launch_bounds__(256)
void vtrans(const float* __restrict__ V, __bf16* __restrict__ Vt) {
  __shared__ float tile[64][65];
  const int bh = blockIdx.x >> 5;
  const int s0 = (blockIdx.x & 31) * 64;
  const int t = threadIdx.x;
  const float* Vb = V + (size_t)bh * 2048 * 64;
#pragma unroll
  for (int i = 0; i < 4; ++i) {
    const int r = i * 16 + (t >> 4);
    const int c4 = (t & 15) * 4;
    float4 v = *(const float4*)(Vb + (s0 + r) * 64 + c4);
    tile[r][c4] = v.x; tile[r][c4 + 1] = v.y;
    tile[r][c4 + 2] = v.z; tile[r][c4 + 3] = v.w;
  }
  __syncthreads();
#pragma unroll
  for (int j = 0; j < 2; ++j) {
    const int d = j * 32 + (t >> 3);
    const int sb = (t & 7) * 8;
    bf16x8 v;
#pragma unroll
    for (int u = 0; u < 8; ++u) v[u] = (__bf16)tile[sb + u][d];
    *(bf16x8*)(Vt + ((size_t)bh * 64 + d) * 2048 + s0 + sb) = v;
  }
}

// ---- main: barrier-free swapped-operand flash diff-attention ----
// Each wave owns 16 q rows. S^T = mfma(K,Qs), O^T += mfma(V^T, P^T).
// K/V^T are pre-converted bf16 in ws; only wave-private Pl LDS remains.
__global__ __launch_bounds__(256, 4)
void diffattn(const float* __restrict__ Q, const __bf16* __restrict__ Kb,
              const __bf16* __restrict__ Vt, const float* __restrict__ LP,
              float* __restrict__ OUT) {
  constexpr int S = 2048, D = 64;
  // 1/sqrt(32) * log2(e), folded into Q before bf16 convert
  constexpr float QSCALE = 0.17677669529663687f * 1.4426950408889634f;

  __shared__ unsigned short Pl[4][2][16][40];  // [wave][br][q][kv], 2-way max (free)

  // XCD swizzle: 1024 wgs % 8 == 0 -> contiguous 128-wg chunk per XCD (4 bh -> 2MB L2)
  const int raw = blockIdx.x;
  const int wg  = (raw & 7) * 128 + (raw >> 3);
  const int bh  = wg >> 5;
  const int qb  = wg & 31;
  const float lam = LP[bh & 15];

  const int tid  = threadIdx.x;
  const int w    = tid >> 6;
  const int lane = tid & 63;
  const int c    = lane & 15;   // q col of fragments
  const int g    = lane >> 4;   // k group
  const int q0   = qb * 64 + w * 16;

  const float*  Qb = Q  + (size_t)bh * S * D;
  const __bf16* Kp = Kb + (size_t)bh * S * D + c * D + 8 * g;  // per-lane K base
  const __bf16* Vp = Vt + (size_t)bh * D * S + c * S + 8 * g;  // per-lane V^T base

  // Q fragments (loop-invariant): B[k = br*32 + 8g + j][n = c]
  bf16x8 bq[2];
#pragma unroll
  for (int br = 0; br < 2; ++br) {
    const float* p = Qb + (q0 + c) * D + br * 32 + 8 * g;
    float4 f0 = *(const float4*)p;
    float4 f1 = *(const float4*)(p + 4);
    bf16x8 v;
    v[0] = (__bf16)(f0.x * QSCALE); v[1] = (__bf16)(f0.y * QSCALE);
    v[2] = (__bf16)(f0.z * QSCALE); v[3] = (__bf16)(f0.w * QSCALE);
    v[4] = (__bf16)(f1.x * QSCALE); v[5] = (__bf16)(f1.y * QSCALE);
    v[6] = (__bf16)(f1.z * QSCALE); v[7] = (__bf16)(f1.w * QSCALE);
    bq[br] = v;
  }

  f32x4 acc[2][4];
#pragma unroll
  for (int br = 0; br < 2; ++br)
#pragma unroll
    for (int dt = 0; dt < 4; ++dt)
      acc[br][dt] = (f32x4){0.f, 0.f, 0.f, 0.f};
  float rsum[2] = {0.f, 0.f};

#define LOADK(ak, ch) do {                                   \
    const __bf16* _p = Kp + (size_t)(ch) * (32 * D);         \
    ak[0][0] = *(const bf16x8*)_p;                           \
    ak[0][1] = *(const bf16x8*)(_p + 32);                    \
    ak[1][0] = *(const bf16x8*)(_p + 16 * D);                \
    ak[1][1] = *(const bf16x8*)(_p + 16 * D + 32);           \
  } while (0)

  bf16x8 akA[2][2], akB[2][2];
  LOADK(akA, 0);

  auto step = [&](bf16x8 (&ak)[2][2], bf16x8 (&akn)[2][2], int ch) {
    LOADK(akn, (ch + 1) & 63);               // prefetch next chunk's K
    bf16x8 av[4];                            // current chunk V^T fragments
#pragma unroll
    for (int dt = 0; dt < 4; ++dt)
      av[dt] = *(const bf16x8*)(Vp + dt * 16 * S + ch * 32);

    // QK^T + exp2 + pack P^T (both softmax branches)
#pragma unroll
    for (int br = 0; br < 2; ++br) {
      f32x4 z = {0.f, 0.f, 0.f, 0.f};
      f32x4 sA = mfma16(ak[0][br], bq[br], z);   // kv rows 4g+r
      f32x4 sB = mfma16(ak[1][br], bq[br], z);   // kv rows 16+4g+r
      float pA[4], pB[4];
#pragma unroll
      for (int r = 0; r < 4; ++r) {
        pA[r] = __builtin_amdgcn_exp2f(sA[r]);
        pB[r] = __builtin_amdgcn_exp2f(sB[r]);
      }
      rsum[br] += (pA[0] + pA[1] + pA[2] + pA[3]) + (pB[0] + pB[1] + pB[2] + pB[3]);
      uint2 uA; uA.x = cvtpk(pA[0], pA[1]); uA.y = cvtpk(pA[2], pA[3]);
      uint2 uB; uB.x = cvtpk(pB[0], pB[1]); uB.y = cvtpk(pB[2], pB[3]);
      *(uint2*)&Pl[w][br][c][4 * g]      = uA;
      *(uint2*)&Pl[w][br][c][16 + 4 * g] = uB;
    }
    asm volatile("s_waitcnt lgkmcnt(0)" ::: "memory");  // wave-private: no barrier
#pragma unroll
    for (int br = 0; br < 2; ++br) {
      bf16x8 bp = *(const bf16x8*)&Pl[w][br][c][8 * g];
#pragma unroll
      for (int dt = 0; dt < 4; ++dt)
        acc[br][dt] = mfma16(av[dt], bp, acc[br][dt]);
    }
  };

  for (int ch2 = 0; ch2 < 32; ++ch2) {   // 64 chunks of 32 kv, 2-deep rotation
    step(akA, akB, 2 * ch2);
    step(akB, akA, 2 * ch2 + 1);
  }
#undef LOADK

  // ---- epilogue: softmax norms, combine, LayerNorm, store ----
  float rs1 = rsum[0], rs2 = rsum[1];
  rs1 += __shfl_xor(rs1, 16); rs1 += __shfl_xor(rs1, 32);
  rs2 += __shfl_xor(rs2, 16); rs2 += __shfl_xor(rs2, 32);
  const float inv1 = 1.0f / rs1;
  const float inv2 = lam / rs2;

  float vals[16];
  float sum = 0.f, sq = 0.f;
#pragma unroll
  for (int dt = 0; dt < 4; ++dt)
#pragma unroll
    for (int r = 0; r < 4; ++r) {
      float x = acc[0][dt][r] * inv1 - acc[1][dt][r] * inv2;
      vals[dt * 4 + r] = x;
      sum += x; sq += x * x;
    }
  sum += __shfl_xor(sum, 16); sum += __shfl_xor(sum, 32);
  sq  += __shfl_xor(sq, 16);  sq  += __shfl_xor(sq, 32);
  const float mean = sum * (1.0f / 64.0f);
  const float var  = sq * (1.0f / 64.0f) - mean * mean;
  const float rstd = rsqrtf(var + 1e-5f) * 0.2f;   // * (1 - LAMBDA_INIT)

  float* op = OUT + (size_t)bh * S * D + (size_t)(q0 + c) * D;
#pragma unroll
  for (int dt = 0; dt < 4; ++dt) {
    float4 o;
    o.x = (vals[dt * 4 + 0] - mean) * rstd;
    o.y = (vals[dt * 4 + 1] - mean) * rstd;
    o.z = (vals[dt * 4 + 2] - mean) * rstd;
    o.w = (vals[dt * 4 + 3] - mean) * rstd;
    *(float4*)(op + 16 * dt + 4 * g) = o;   // d = 16dt + 4g + r contiguous
  }
}

extern "C" void kernel_launch(void* const* d_in, const int* in_sizes, int n_in,
                              void* d_out, int out_size, void* d_ws, size_t ws_size,
                              hipStream_t stream) {
  (void)in_sizes; (void)n_in; (void)out_size; (void)ws_size;
  const float* q  = (const float*)d_in[0];
  const float* k  = (const float*)d_in[1];
  const float* v  = (const float*)d_in[2];
  const float* lp = (const float*)d_in[3];
  float* out = (float*)d_out;

  __bf16* kbf = (__bf16*)d_ws;                              // 8 MB
  __bf16* vtg = (__bf16*)((char*)d_ws + (8u << 20));        // 8 MB

  cvt_k <<<dim3(2048), dim3(256), 0, stream>>>(k, kbf);
  vtrans<<<dim3(1024), dim3(256), 0, stream>>>(v, vtg);
  diffattn<<<dim3(1024), dim3(256), 0, stream>>>(q, kbf, vtg, lp, out);
}

// Round 3
// 246.589 us; speedup vs baseline: 1.0027x; 1.0027x over previous
//
#include <hip/hip_runtime.h>

typedef __bf16 bf16x8 __attribute__((ext_vector_type(8)));
typedef float f32x4 __attribute__((ext_vector_type(4)));

static __device__ __forceinline__ f32x4 mfma16(bf16x8 a, bf16x8 b, f32x4 c) {
  return __builtin_amdgcn_mfma_f32_16x16x32_bf16(a, b, c, 0, 0, 0);
}
static __device__ __forceinline__ unsigned cvtpk(float lo, float hi) {
  unsigned r;
  asm("v_cvt_pk_bf16_f32 %0, %1, %2" : "=v"(r) : "v"(lo), "v"(hi));
  return r;
}

// ---- pre-pass 1: K fp32 -> bf16, same [bh][s][d] layout ----
__global__ __launch_bounds__(256)
void cvt_k(const float* __restrict__ K, __bf16* __restrict__ Kb) {
  const int i = (blockIdx.x * 256 + threadIdx.x) * 8;
  float4 a = *(const float4*)(K + i);
  float4 b = *(const float4*)(K + i + 4);
  bf16x8 v;
  v[0] = (__bf16)a.x; v[1] = (__bf16)a.y; v[2] = (__bf16)a.z; v[3] = (__bf16)a.w;
  v[4] = (__bf16)b.x; v[5] = (__bf16)b.y; v[6] = (__bf16)b.z; v[7] = (__bf16)b.w;
  *(bf16x8*)(Kb + i) = v;
}

// ---- pre-pass 2: V [bh][s][64] fp32 -> V^T bf16 [bh][d][2048] ----
__global__ __launch_bounds__(256)
void vtrans(const float* __restrict__ V, __bf16* __restrict__ Vt) {
  __shared__ float tile[64][65];
  const int bh = blockIdx.x >> 5;
  const int s0 = (blockIdx.x & 31) * 64;
  const int t = threadIdx.x;
  const float* Vb = V + (size_t)bh * 2048 * 64;
#pragma unroll
  for (int i = 0; i < 4; ++i) {
    const int r = i * 16 + (t >> 4);
    const int c4 = (t & 15) * 4;
    float4 v = *(const float4*)(Vb + (s0 + r) * 64 + c4);
    tile[r][c4] = v.x; tile[r][c4 + 1] = v.y;
    tile[r][c4 + 2] = v.z; tile[r][c4 + 3] = v.w;
  }
  __syncthreads();
#pragma unroll
  for (int j = 0; j < 2; ++j) {
    const int d = j * 32 + (t >> 3);
    const int sb = (t & 7) * 8;
    bf16x8 v;
#pragma unroll
    for (int u = 0; u < 8; ++u) v[u] = (__bf16)tile[sb + u][d];
    *(bf16x8*)(Vt + ((size_t)bh * 64 + d) * 2048 + s0 + sb) = v;
  }
}

// ---- main: barrier-free swapped-operand flash diff-attention ----
// R3 change vs R2: main loop pinned to NO unroll (#pragma unroll 1) to keep
// code size ~2KB << 32KB I$. Everything else identical (single-variable A/B).
__global__ __launch_bounds__(256, 4)
void diffattn(const float* __restrict__ Q, const __bf16* __restrict__ Kb,
              const __bf16* __restrict__ Vt, const float* __restrict__ LP,
              float* __restrict__ OUT) {
  constexpr int S = 2048, D = 64;
  constexpr float QSCALE = 0.17677669529663687f * 1.4426950408889634f;

  __shared__ unsigned short Pl[4][2][16][40];  // [wave][br][q][kv]

  const int raw = blockIdx.x;
  const int wg  = (raw & 7) * 128 + (raw >> 3);   // XCD swizzle (1024 % 8 == 0)
  const int bh  = wg >> 5;
  const int qb  = wg & 31;
  const float lam = LP[bh & 15];

  const int tid  = threadIdx.x;
  const int w    = tid >> 6;
  const int lane = tid & 63;
  const int c    = lane & 15;
  const int g    = lane >> 4;
  const int q0   = qb * 64 + w * 16;

  const float*  Qb = Q  + (size_t)bh * S * D;
  const __bf16* Kp = Kb + (size_t)bh * S * D + c * D + 8 * g;
  const __bf16* Vp = Vt + (size_t)bh * D * S + c * S + 8 * g;

  bf16x8 bq[2];
#pragma unroll
  for (int br = 0; br < 2; ++br) {
    const float* p = Qb + (q0 + c) * D + br * 32 + 8 * g;
    float4 f0 = *(const float4*)p;
    float4 f1 = *(const float4*)(p + 4);
    bf16x8 v;
    v[0] = (__bf16)(f0.x * QSCALE); v[1] = (__bf16)(f0.y * QSCALE);
    v[2] = (__bf16)(f0.z * QSCALE); v[3] = (__bf16)(f0.w * QSCALE);
    v[4] = (__bf16)(f1.x * QSCALE); v[5] = (__bf16)(f1.y * QSCALE);
    v[6] = (__bf16)(f1.z * QSCALE); v[7] = (__bf16)(f1.w * QSCALE);
    bq[br] = v;
  }

  f32x4 acc[2][4];
#pragma unroll
  for (int br = 0; br < 2; ++br)
#pragma unroll
    for (int dt = 0; dt < 4; ++dt)
      acc[br][dt] = (f32x4){0.f, 0.f, 0.f, 0.f};
  float rsum[2] = {0.f, 0.f};

#define LOADK(ak, ch) do {                                   \
    const __bf16* _p = Kp + (size_t)(ch) * (32 * D);         \
    ak[0][0] = *(const bf16x8*)_p;                           \
    ak[0][1] = *(const bf16x8*)(_p + 32);                    \
    ak[1][0] = *(const bf16x8*)(_p + 16 * D);                \
    ak[1][1] = *(const bf16x8*)(_p + 16 * D + 32);           \
  } while (0)

#define STEP(akc, akn, ch) do {                                           \
    LOADK(akn, ((ch) + 1) & 63);                                          \
    bf16x8 av[4];                                                         \
    _Pragma("unroll")                                                     \
    for (int dt = 0; dt < 4; ++dt)                                        \
      av[dt] = *(const bf16x8*)(Vp + dt * 16 * S + (ch) * 32);            \
    _Pragma("unroll")                                                     \
    for (int br = 0; br < 2; ++br) {                                      \
      f32x4 z = {0.f, 0.f, 0.f, 0.f};                                     \
      f32x4 sA = mfma16(akc[0][br], bq[br], z);                           \
      f32x4 sB = mfma16(akc[1][br], bq[br], z);                           \
      float pA[4], pB[4];                                                 \
      _Pragma("unroll")                                                   \
      for (int r = 0; r < 4; ++r) {                                       \
        pA[r] = __builtin_amdgcn_exp2f(sA[r]);                            \
        pB[r] = __builtin_amdgcn_exp2f(sB[r]);                            \
      }                                                                   \
      rsum[br] += (pA[0]+pA[1]+pA[2]+pA[3]) + (pB[0]+pB[1]+pB[2]+pB[3]);  \
      uint2 uA; uA.x = cvtpk(pA[0], pA[1]); uA.y = cvtpk(pA[2], pA[3]);   \
      uint2 uB; uB.x = cvtpk(pB[0], pB[1]); uB.y = cvtpk(pB[2], pB[3]);   \
      *(uint2*)&Pl[w][br][c][4 * g]      = uA;                            \
      *(uint2*)&Pl[w][br][c][16 + 4 * g] = uB;                            \
    }                                                                     \
    asm volatile("s_waitcnt lgkmcnt(0)" ::: "memory");                    \
    _Pragma("unroll")                                                     \
    for (int br = 0; br < 2; ++br) {                                      \
      bf16x8 bp = *(const bf16x8*)&Pl[w][br][c][8 * g];                   \
      _Pragma("unroll")                                                   \
      for (int dt = 0; dt < 4; ++dt)                                      \
        acc[br][dt] = mfma16(av[dt], bp, acc[br][dt]);                    \
    }                                                                     \
  } while (0)

  bf16x8 akA[2][2], akB[2][2];
  LOADK(akA, 0);

#pragma unroll 1
  for (int ch = 0; ch < 64; ch += 2) {   // NOT unrolled: keep code in I$
    STEP(akA, akB, ch);
    STEP(akB, akA, ch + 1);
  }
#undef STEP
#undef LOADK

  // ---- epilogue ----
  float rs1 = rsum[0], rs2 = rsum[1];
  rs1 += __shfl_xor(rs1, 16); rs1 += __shfl_xor(rs1, 32);
  rs2 += __shfl_xor(rs2, 16); rs2 += __shfl_xor(rs2, 32);
  const float inv1 = 1.0f / rs1;
  const float inv2 = lam / rs2;

  float vals[16];
  float sum = 0.f, sq = 0.f;
#pragma unroll
  for (int dt = 0; dt < 4; ++dt)
#pragma unroll
    for (int r = 0; r < 4; ++r) {
      float x = acc[0][dt][r] * inv1 - acc[1][dt][r] * inv2;
      vals[dt * 4 + r] = x;
      sum += x; sq += x * x;
    }
  sum += __shfl_xor(sum, 16); sum += __shfl_xor(sum, 32);
  sq  += __shfl_xor(sq, 16);  sq  += __shfl_xor(sq, 32);
  const float mean = sum * (1.0f / 64.0f);
  const float var  = sq * (1.0f / 64.0f) - mean * mean;
  const float rstd = rsqrtf(var + 1e-5f) * 0.2f;

  float* op = OUT + (size_t)bh * S * D + (size_t)(q0 + c) * D;
#pragma unroll
  for (int dt = 0; dt < 4; ++dt) {
    float4 o;
    o.x = (vals[dt * 4 + 0] - mean) * rstd;
    o.y = (vals[dt * 4 + 1] - mean) * rstd;
    o.z = (vals[dt * 4 + 2] - mean) * rstd;
    o.w = (vals[dt * 4 + 3] - mean) * rstd;
    *(float4*)(op + 16 * dt + 4 * g) = o;
  }
}

extern "C" void kernel_launch(void* const* d_in, const int* in_sizes, int n_in,
                              void* d_out, int out_size, void* d_ws, size_t ws_size,
                              hipStream_t stream) {
  (void)in_sizes; (void)n_in; (void)out_size; (void)ws_size;
  const float* q  = (const float*)d_in[0];
  const float* k  = (const float*)d_in[1];
  const float* v  = (const float*)d_in[2];
  const float* lp = (const float*)d_in[3];
  float* out = (float*)d_out;

  __bf16* kbf = (__bf16*)d_ws;                              // 8 MB
  __bf16* vtg = (__bf16*)((char*)d_ws + (8u << 20));        // 8 MB

  cvt_k <<<dim3(2048), dim3(256), 0, stream>>>(k, kbf);
  vtrans<<<dim3(1024), dim3(256), 0, stream>>>(v, vtg);
  diffattn<<<dim3(1024), dim3(256), 0, stream>>>(q, kbf, vtg, lp, out);
}

// Round 5
// 79.174 us; speedup vs baseline: 3.1228x; 3.1145x over previous
//
#include <hip/hip_runtime.h>

typedef __bf16 bf16x8 __attribute__((ext_vector_type(8)));
typedef float f32x4 __attribute__((ext_vector_type(4)));

static __device__ __forceinline__ f32x4 mfma16(bf16x8 a, bf16x8 b, f32x4 c) {
  return __builtin_amdgcn_mfma_f32_16x16x32_bf16(a, b, c, 0, 0, 0);
}
static __device__ __forceinline__ unsigned cvtpk(float lo, float hi) {
  unsigned r;
  asm("v_cvt_pk_bf16_f32 %0, %1, %2" : "=v"(r) : "v"(lo), "v"(hi));
  return r;
}

// ---- pre-pass 1: K fp32 -> bf16 packed in MFMA-fragment order ----
// KS[bh][ch][t2*2+br][g][c][j] : 1KB blocks; a wave's fragment load is one
// contiguous 1KB region (lane (c,g) reads 16B at g*256 + c*16).
__global__ __launch_bounds__(256)
void kpack(const float* __restrict__ K, __bf16* __restrict__ KS) {
  const int bh = blockIdx.x >> 6, ch = blockIdx.x & 63;
  const int t = threadIdx.x;
  const int t2 = t >> 7, br = (t >> 6) & 1, g = (t >> 4) & 3, c = t & 15;
  const float* src = K + ((size_t)bh * 2048 + ch * 32 + t2 * 16 + c) * 64 + br * 32 + g * 8;
  float4 f0 = *(const float4*)src;
  float4 f1 = *(const float4*)(src + 4);
  bf16x8 v;
  v[0] = (__bf16)f0.x; v[1] = (__bf16)f0.y; v[2] = (__bf16)f0.z; v[3] = (__bf16)f0.w;
  v[4] = (__bf16)f1.x; v[5] = (__bf16)f1.y; v[6] = (__bf16)f1.z; v[7] = (__bf16)f1.w;
  *(bf16x8*)(KS + (size_t)bh * 131072 + ch * 2048 + t * 8) = v;   // fully coalesced
}

// ---- pre-pass 2: V fp32 [bh][s][64] -> V^T bf16 packed fragment order ----
// VS[bh][ch][dt][g][c][j] = V[bh][ch*32+8g+j][16dt+c] : 1KB blocks.
__global__ __launch_bounds__(256)
void vpack(const float* __restrict__ V, __bf16* __restrict__ VS) {
  __shared__ float tile[64][65];
  const int bh = blockIdx.x >> 5;
  const int s0 = (blockIdx.x & 31) * 64;
  const int t = threadIdx.x;
  const float* Vb = V + (size_t)bh * 2048 * 64;
#pragma unroll
  for (int i = 0; i < 4; ++i) {
    const int r = i * 16 + (t >> 4);
    const int c4 = (t & 15) * 4;
    float4 v = *(const float4*)(Vb + (s0 + r) * 64 + c4);
    tile[r][c4] = v.x; tile[r][c4 + 1] = v.y;
    tile[r][c4 + 2] = v.z; tile[r][c4 + 3] = v.w;
  }
  __syncthreads();
  const int dt = t >> 6, g = (t >> 4) & 3, c = t & 15;
#pragma unroll
  for (int h = 0; h < 2; ++h) {
    const int ch = (blockIdx.x & 31) * 2 + h;
    bf16x8 v;
#pragma unroll
    for (int j = 0; j < 8; ++j) v[j] = (__bf16)tile[h * 32 + 8 * g + j][16 * dt + c];
    *(bf16x8*)(VS + (size_t)bh * 131072 + ch * 2048 + dt * 512 + g * 128 + c * 8) = v;
  }
}

// ---- main: swapped-operand flash diff-attention, fragment-packed loads ----
// Every K/V fragment load = contiguous coalesced 1KB wave-load. Compute
// structure identical to the verified R3 kernel (LDS P^T round-trip); the
// vmcnt-draining "memory"-clobber asm is replaced by sched_barrier(0) +
// same-wave in-order DS semantics. 32 q rows/wave, 512 blocks.
__global__ __launch_bounds__(256, 2)
void diffattn(const float* __restrict__ Q, const __bf16* __restrict__ KS,
              const __bf16* __restrict__ VS, const float* __restrict__ LP,
              float* __restrict__ OUT) {
  constexpr int S = 2048, D = 64;
  constexpr float QSCALE = 0.17677669529663687f * 1.4426950408889634f;

  __shared__ __align__(16) unsigned short Pl[4][2][16][40];  // [wave][br][q][kv]

  const int raw = blockIdx.x;
  const int wg  = (raw & 7) * 64 + (raw >> 3);   // XCD swizzle (512 % 8 == 0)
  const int bh  = wg >> 4;
  const int qb  = wg & 15;
  const float lam = LP[bh & 15];

  const int tid  = threadIdx.x;
  const int w    = tid >> 6;
  const int lane = tid & 63;
  const int c    = lane & 15;
  const int g    = lane >> 4;
  const int q0   = qb * 128 + w * 32;            // 32 q rows per wave

  const float*  Qb    = Q  + (size_t)bh * S * D;
  const __bf16* Kbase = KS + (size_t)bh * 131072 + g * 128 + c * 8;
  const __bf16* Vbase = VS + (size_t)bh * 131072 + g * 128 + c * 8;

  // Q fragments: bq[qt][br], B[k = br*32+8g+j][n = c]
  bf16x8 bq[2][2];
#pragma unroll
  for (int qt = 0; qt < 2; ++qt)
#pragma unroll
    for (int br = 0; br < 2; ++br) {
      const float* p = Qb + (q0 + qt * 16 + c) * D + br * 32 + 8 * g;
      float4 f0 = *(const float4*)p;
      float4 f1 = *(const float4*)(p + 4);
      bf16x8 v;
      v[0] = (__bf16)(f0.x * QSCALE); v[1] = (__bf16)(f0.y * QSCALE);
      v[2] = (__bf16)(f0.z * QSCALE); v[3] = (__bf16)(f0.w * QSCALE);
      v[4] = (__bf16)(f1.x * QSCALE); v[5] = (__bf16)(f1.y * QSCALE);
      v[6] = (__bf16)(f1.z * QSCALE); v[7] = (__bf16)(f1.w * QSCALE);
      bq[qt][br] = v;
    }

  f32x4 acc[2][2][4];
#pragma unroll
  for (int qt = 0; qt < 2; ++qt)
#pragma unroll
    for (int br = 0; br < 2; ++br)
#pragma unroll
      for (int dt = 0; dt < 4; ++dt)
        acc[qt][br][dt] = (f32x4){0.f, 0.f, 0.f, 0.f};
  float rsum[2][2] = {{0.f, 0.f}, {0.f, 0.f}};

#define LOADK(ak, ch) do {                                             \
    const __bf16* _p = Kbase + (size_t)(ch) * 2048;                    \
    ak[0][0] = *(const bf16x8*)_p;                                     \
    ak[0][1] = *(const bf16x8*)(_p + 512);                             \
    ak[1][0] = *(const bf16x8*)(_p + 1024);                            \
    ak[1][1] = *(const bf16x8*)(_p + 1536);                            \
  } while (0)

#define LOADV(av, ch) do {                                             \
    const __bf16* _p = Vbase + (size_t)(ch) * 2048;                    \
    _Pragma("unroll")                                                  \
    for (int dt = 0; dt < 4; ++dt)                                     \
      av[dt] = *(const bf16x8*)(_p + dt * 512);                        \
  } while (0)

#define STEP(akc, akn, avc, avn, ch) do {                                 \
    LOADK(akn, ((ch) + 1) & 63);                                          \
    LOADV(avn, ((ch) + 1) & 63);                                          \
    _Pragma("unroll")                                                     \
    for (int qt = 0; qt < 2; ++qt) {                                      \
      _Pragma("unroll")                                                   \
      for (int br = 0; br < 2; ++br) {                                    \
        f32x4 z = {0.f, 0.f, 0.f, 0.f};                                   \
        f32x4 sA = mfma16(akc[0][br], bq[qt][br], z);                     \
        f32x4 sB = mfma16(akc[1][br], bq[qt][br], z);                     \
        float pA[4], pB[4];                                               \
        _Pragma("unroll")                                                 \
        for (int r = 0; r < 4; ++r) {                                     \
          pA[r] = __builtin_amdgcn_exp2f(sA[r]);                          \
          pB[r] = __builtin_amdgcn_exp2f(sB[r]);                          \
        }                                                                 \
        rsum[qt][br] += (pA[0]+pA[1]+pA[2]+pA[3]) + (pB[0]+pB[1]+pB[2]+pB[3]); \
        uint2 uA; uA.x = cvtpk(pA[0], pA[1]); uA.y = cvtpk(pA[2], pA[3]); \
        uint2 uB; uB.x = cvtpk(pB[0], pB[1]); uB.y = cvtpk(pB[2], pB[3]); \
        *(uint2*)&Pl[w][br][c][4 * g]      = uA;                          \
        *(uint2*)&Pl[w][br][c][16 + 4 * g] = uB;                          \
      }                                                                   \
      __builtin_amdgcn_sched_barrier(0);  /* DS in-order: no wait needed */ \
      _Pragma("unroll")                                                   \
      for (int br = 0; br < 2; ++br) {                                    \
        bf16x8 bp = *(const bf16x8*)&Pl[w][br][c][8 * g];                 \
        _Pragma("unroll")                                                 \
        for (int dt = 0; dt < 4; ++dt)                                    \
          acc[qt][br][dt] = mfma16(avc[dt], bp, acc[qt][br][dt]);         \
      }                                                                   \
      __builtin_amdgcn_sched_barrier(0);  /* pin reads before next qt's writes */ \
    }                                                                     \
  } while (0)

  bf16x8 akA[2][2], akB[2][2], avA[4], avB[4];
  LOADK(akA, 0);
  LOADV(avA, 0);

#pragma unroll 1
  for (int ch = 0; ch < 64; ch += 2) {
    STEP(akA, akB, avA, avB, ch);
    STEP(akB, akA, avB, avA, ch + 1);
  }
#undef STEP
#undef LOADV
#undef LOADK

  // ---- epilogue: softmax norms, combine, LayerNorm, store ----
#pragma unroll
  for (int qt = 0; qt < 2; ++qt) {
    float rs1 = rsum[qt][0], rs2 = rsum[qt][1];
    rs1 += __shfl_xor(rs1, 16); rs1 += __shfl_xor(rs1, 32);
    rs2 += __shfl_xor(rs2, 16); rs2 += __shfl_xor(rs2, 32);
    const float inv1 = 1.0f / rs1;
    const float inv2 = lam / rs2;

    float vals[16];
    float sum = 0.f, sq = 0.f;
#pragma unroll
    for (int dt = 0; dt < 4; ++dt)
#pragma unroll
      for (int r = 0; r < 4; ++r) {
        float x = acc[qt][0][dt][r] * inv1 - acc[qt][1][dt][r] * inv2;
        vals[dt * 4 + r] = x;
        sum += x; sq += x * x;
      }
    sum += __shfl_xor(sum, 16); sum += __shfl_xor(sum, 32);
    sq  += __shfl_xor(sq, 16);  sq  += __shfl_xor(sq, 32);
    const float mean = sum * (1.0f / 64.0f);
    const float var  = sq * (1.0f / 64.0f) - mean * mean;
    const float rstd = rsqrtf(var + 1e-5f) * 0.2f;   // * (1 - LAMBDA_INIT)

    float* op = OUT + (size_t)bh * S * D + (size_t)(q0 + qt * 16 + c) * D;
#pragma unroll
    for (int dt = 0; dt < 4; ++dt) {
      float4 o;
      o.x = (vals[dt * 4 + 0] - mean) * rstd;
      o.y = (vals[dt * 4 + 1] - mean) * rstd;
      o.z = (vals[dt * 4 + 2] - mean) * rstd;
      o.w = (vals[dt * 4 + 3] - mean) * rstd;
      *(float4*)(op + 16 * dt + 4 * g) = o;
    }
  }
}

extern "C" void kernel_launch(void* const* d_in, const int* in_sizes, int n_in,
                              void* d_out, int out_size, void* d_ws, size_t ws_size,
                              hipStream_t stream) {
  (void)in_sizes; (void)n_in; (void)out_size; (void)ws_size;
  const float* q  = (const float*)d_in[0];
  const float* k  = (const float*)d_in[1];
  const float* v  = (const float*)d_in[2];
  const float* lp = (const float*)d_in[3];
  float* out = (float*)d_out;

  __bf16* ks = (__bf16*)d_ws;                              // 8 MiB
  __bf16* vs = (__bf16*)((char*)d_ws + (8u << 20));        // 8 MiB

  kpack<<<dim3(2048), dim3(256), 0, stream>>>(k, ks);
  vpack<<<dim3(1024), dim3(256), 0, stream>>>(v, vs);
  diffattn<<<dim3(512), dim3(256), 0, stream>>>(q, ks, vs, lp, out);
}

// Round 7
// 77.134 us; speedup vs baseline: 3.2054x; 1.0264x over previous
//
#include <hip/hip_runtime.h>

typedef __bf16 bf16x8 __attribute__((ext_vector_type(8)));
typedef float f32x4 __attribute__((ext_vector_type(4)));

static __device__ __forceinline__ f32x4 mfma16(bf16x8 a, bf16x8 b, f32x4 c) {
  return __builtin_amdgcn_mfma_f32_16x16x32_bf16(a, b, c, 0, 0, 0);
}
static __device__ __forceinline__ unsigned cvtpk(float lo, float hi) {
  unsigned r;
  asm("v_cvt_pk_bf16_f32 %0, %1, %2" : "=v"(r) : "v"(lo), "v"(hi));
  return r;
}

// ---- pre-pass 1: K fp32 -> bf16 packed in MFMA-fragment order ----
// KS[bh][ch][t2*2+br][g][c][j] : 1KB blocks; a wave's fragment load is one
// contiguous 1KB region (lane (c,g) reads 16B at g*256 + c*16).
__global__ __launch_bounds__(256)
void kpack(const float* __restrict__ K, __bf16* __restrict__ KS) {
  const int bh = blockIdx.x >> 6, ch = blockIdx.x & 63;
  const int t = threadIdx.x;
  const int t2 = t >> 7, br = (t >> 6) & 1, g = (t >> 4) & 3, c = t & 15;
  const float* src = K + ((size_t)bh * 2048 + ch * 32 + t2 * 16 + c) * 64 + br * 32 + g * 8;
  float4 f0 = *(const float4*)src;
  float4 f1 = *(const float4*)(src + 4);
  bf16x8 v;
  v[0] = (__bf16)f0.x; v[1] = (__bf16)f0.y; v[2] = (__bf16)f0.z; v[3] = (__bf16)f0.w;
  v[4] = (__bf16)f1.x; v[5] = (__bf16)f1.y; v[6] = (__bf16)f1.z; v[7] = (__bf16)f1.w;
  *(bf16x8*)(KS + (size_t)bh * 131072 + ch * 2048 + t * 8) = v;   // fully coalesced
}

// ---- pre-pass 2: V fp32 [bh][s][64] -> V^T bf16 packed fragment order ----
// VS[bh][ch][dt][g][c][j] = V[bh][ch*32+8g+j][16dt+c] : 1KB blocks.
__global__ __launch_bounds__(256)
void vpack(const float* __restrict__ V, __bf16* __restrict__ VS) {
  __shared__ float tile[64][65];
  const int bh = blockIdx.x >> 5;
  const int s0 = (blockIdx.x & 31) * 64;
  const int t = threadIdx.x;
  const float* Vb = V + (size_t)bh * 2048 * 64;
#pragma unroll
  for (int i = 0; i < 4; ++i) {
    const int r = i * 16 + (t >> 4);
    const int c4 = (t & 15) * 4;
    float4 v = *(const float4*)(Vb + (s0 + r) * 64 + c4);
    tile[r][c4] = v.x; tile[r][c4 + 1] = v.y;
    tile[r][c4 + 2] = v.z; tile[r][c4 + 3] = v.w;
  }
  __syncthreads();
  const int dt = t >> 6, g = (t >> 4) & 3, c = t & 15;
#pragma unroll
  for (int h = 0; h < 2; ++h) {
    const int ch = (blockIdx.x & 31) * 2 + h;
    bf16x8 v;
#pragma unroll
    for (int j = 0; j < 8; ++j) v[j] = (__bf16)tile[h * 32 + 8 * g + j][16 * dt + c];
    *(bf16x8*)(VS + (size_t)bh * 131072 + ch * 2048 + dt * 512 + g * 128 + c * 8) = v;
  }
}

// ---- main: cross-step pipelined swapped-operand flash diff-attention ----
// R7 vs R6 (which failed): the P-LDS write->read edge spans a step, and R6's
// mixed-type accesses (uint2 store / bf16x8 load on a short array) let the
// scheduler reorder across it. Fix: ALL P accesses are uint2 (exact alias
// info) + sched_barrier(0) at each step boundary pinning cross-step order.
// Pipeline per step: read P(ch-1) -> prefetch K(ch+1) ->
//   QK(ch)+exp+pack+write P(ch) -> PV(ch-1) -> prefetch V(ch+1) -> SBAR.
__global__ __launch_bounds__(256, 2)
void diffattn(const float* __restrict__ Q, const __bf16* __restrict__ KS,
              const __bf16* __restrict__ VS, const float* __restrict__ LP,
              float* __restrict__ OUT) {
  constexpr int S = 2048, D = 64;
  constexpr float QSCALE = 0.17677669529663687f * 1.4426950408889634f;

  // [parity][wave][qt][br][q][10 uint2] : 40 KB. Row = 80B (same as R5's 40 shorts).
  __shared__ __align__(16) uint2 Pl[2][4][2][2][16][10];

  const int raw = blockIdx.x;
  const int wg  = (raw & 7) * 64 + (raw >> 3);   // XCD swizzle (512 % 8 == 0)
  const int bh  = wg >> 4;
  const int qb  = wg & 15;
  const float lam = LP[bh & 15];

  const int tid  = threadIdx.x;
  const int w    = tid >> 6;
  const int lane = tid & 63;
  const int c    = lane & 15;
  const int g    = lane >> 4;
  const int q0   = qb * 128 + w * 32;            // 32 q rows per wave

  const float*  Qb    = Q  + (size_t)bh * S * D;
  const __bf16* Kbase = KS + (size_t)bh * 131072 + g * 128 + c * 8;
  const __bf16* Vbase = VS + (size_t)bh * 131072 + g * 128 + c * 8;

  // Q fragments: bq[qt][br], B[k = br*32+8g+j][n = c]
  bf16x8 bq[2][2];
#pragma unroll
  for (int qt = 0; qt < 2; ++qt)
#pragma unroll
    for (int br = 0; br < 2; ++br) {
      const float* p = Qb + (q0 + qt * 16 + c) * D + br * 32 + 8 * g;
      float4 f0 = *(const float4*)p;
      float4 f1 = *(const float4*)(p + 4);
      bf16x8 v;
      v[0] = (__bf16)(f0.x * QSCALE); v[1] = (__bf16)(f0.y * QSCALE);
      v[2] = (__bf16)(f0.z * QSCALE); v[3] = (__bf16)(f0.w * QSCALE);
      v[4] = (__bf16)(f1.x * QSCALE); v[5] = (__bf16)(f1.y * QSCALE);
      v[6] = (__bf16)(f1.z * QSCALE); v[7] = (__bf16)(f1.w * QSCALE);
      bq[qt][br] = v;
    }

  f32x4 acc[2][2][4];
#pragma unroll
  for (int qt = 0; qt < 2; ++qt)
#pragma unroll
    for (int br = 0; br < 2; ++br)
#pragma unroll
      for (int dt = 0; dt < 4; ++dt)
        acc[qt][br][dt] = (f32x4){0.f, 0.f, 0.f, 0.f};
  float rsum[2][2] = {{0.f, 0.f}, {0.f, 0.f}};

#define LOADK(ak, ch) do {                                             \
    const __bf16* _p = Kbase + (size_t)(ch) * 2048;                    \
    ak[0][0] = *(const bf16x8*)_p;                                     \
    ak[0][1] = *(const bf16x8*)(_p + 512);                             \
    ak[1][0] = *(const bf16x8*)(_p + 1024);                            \
    ak[1][1] = *(const bf16x8*)(_p + 1536);                            \
  } while (0)

#define LOADV(av, ch) do {                                             \
    const __bf16* _p = Vbase + (size_t)(ch) * 2048;                    \
    _Pragma("unroll")                                                  \
    for (int dt = 0; dt < 4; ++dt)                                     \
      av[dt] = *(const bf16x8*)(_p + dt * 512);                        \
  } while (0)

  // QK + exp + pack + DS-write (uint2) for chunk ch into parity PW
#define QKPACK(PW, kcur) do {                                             \
    _Pragma("unroll")                                                     \
    for (int qt = 0; qt < 2; ++qt)                                        \
      _Pragma("unroll")                                                   \
      for (int br = 0; br < 2; ++br) {                                    \
        f32x4 z = {0.f, 0.f, 0.f, 0.f};                                   \
        f32x4 sA = mfma16(kcur[0][br], bq[qt][br], z);                    \
        f32x4 sB = mfma16(kcur[1][br], bq[qt][br], z);                    \
        float pA[4], pB[4];                                               \
        _Pragma("unroll")                                                 \
        for (int r = 0; r < 4; ++r) {                                     \
          pA[r] = __builtin_amdgcn_exp2f(sA[r]);                          \
          pB[r] = __builtin_amdgcn_exp2f(sB[r]);                          \
        }                                                                 \
        rsum[qt][br] += (pA[0]+pA[1]+pA[2]+pA[3]) + (pB[0]+pB[1]+pB[2]+pB[3]); \
        uint2 uA; uA.x = cvtpk(pA[0], pA[1]); uA.y = cvtpk(pA[2], pA[3]); \
        uint2 uB; uB.x = cvtpk(pB[0], pB[1]); uB.y = cvtpk(pB[2], pB[3]); \
        Pl[PW][w][qt][br][c][g]     = uA;    /* kv 4g..4g+3   (bytes 8g)   */ \
        Pl[PW][w][qt][br][c][4 + g] = uB;    /* kv 16+4g..    (bytes 32+8g)*/ \
      }                                                                   \
  } while (0)

  // read P(prev chunk) as uint2 pairs -> bf16x8 B-fragments
#define READP(pb, PR) do {                                                \
    _Pragma("unroll")                                                     \
    for (int qt = 0; qt < 2; ++qt)                                        \
      _Pragma("unroll")                                                   \
      for (int br = 0; br < 2; ++br) {                                    \
        uint2 lo = Pl[PR][w][qt][br][c][2 * g];                           \
        uint2 hi = Pl[PR][w][qt][br][c][2 * g + 1];                       \
        uint4 u = make_uint4(lo.x, lo.y, hi.x, hi.y);                     \
        pb[qt][br] = __builtin_bit_cast(bf16x8, u);                       \
      }                                                                   \
  } while (0)

  // full pipelined step: PV lags QK by one chunk
#define STEP(PR, PW, kcur, knext, vprev, ch) do {                         \
    bf16x8 pb[2][2];                                                      \
    READP(pb, PR);                                                        \
    LOADK(knext, ((ch) + 1) & 63);                                        \
    QKPACK(PW, kcur);                                                     \
    _Pragma("unroll")                                                     \
    for (int qt = 0; qt < 2; ++qt)                                        \
      _Pragma("unroll")                                                   \
      for (int br = 0; br < 2; ++br)                                      \
        _Pragma("unroll")                                                 \
        for (int dt = 0; dt < 4; ++dt)                                    \
          acc[qt][br][dt] = mfma16(vprev[dt], pb[qt][br], acc[qt][br][dt]); \
    LOADV(vprev, ((ch) + 1) & 63);                                        \
    __builtin_amdgcn_sched_barrier(0);  /* pin: next step's P-read stays  \
                                           after this step's P-writes */  \
  } while (0)

  bf16x8 k0[2][2], k1[2][2], v0[4], v1[4];
  LOADK(k0, 0); LOADV(v0, 0);
  LOADK(k1, 1); LOADV(v1, 1);
  QKPACK(0, k0);                       // chunk 0 scores -> Pl[0]; no PV yet
  __builtin_amdgcn_sched_barrier(0);

#pragma unroll 1
  for (int c2 = 0; c2 < 31; ++c2) {    // ch = 1..62
    STEP(0, 1, k1, k0, v0, 2 * c2 + 1);
    STEP(1, 0, k0, k1, v1, 2 * c2 + 2);
  }
  STEP(0, 1, k1, k0, v0, 63);          // QK(63) -> Pl[1], PV(62)

  // final PV for chunk 63 (V(63) sits in v1, loaded at step 62)
  {
    bf16x8 pb[2][2];
    READP(pb, 1);
#pragma unroll
    for (int qt = 0; qt < 2; ++qt)
#pragma unroll
      for (int br = 0; br < 2; ++br)
#pragma unroll
        for (int dt = 0; dt < 4; ++dt)
          acc[qt][br][dt] = mfma16(v1[dt], pb[qt][br], acc[qt][br][dt]);
  }
#undef STEP
#undef READP
#undef QKPACK
#undef LOADV
#undef LOADK

  // ---- epilogue: softmax norms, combine, LayerNorm, store ----
#pragma unroll
  for (int qt = 0; qt < 2; ++qt) {
    float rs1 = rsum[qt][0], rs2 = rsum[qt][1];
    rs1 += __shfl_xor(rs1, 16); rs1 += __shfl_xor(rs1, 32);
    rs2 += __shfl_xor(rs2, 16); rs2 += __shfl_xor(rs2, 32);
    const float inv1 = 1.0f / rs1;
    const float inv2 = lam / rs2;

    float vals[16];
    float sum = 0.f, sq = 0.f;
#pragma unroll
    for (int dt = 0; dt < 4; ++dt)
#pragma unroll
      for (int r = 0; r < 4; ++r) {
        float x = acc[qt][0][dt][r] * inv1 - acc[qt][1][dt][r] * inv2;
        vals[dt * 4 + r] = x;
        sum += x; sq += x * x;
      }
    sum += __shfl_xor(sum, 16); sum += __shfl_xor(sum, 32);
    sq  += __shfl_xor(sq, 16);  sq  += __shfl_xor(sq, 32);
    const float mean = sum * (1.0f / 64.0f);
    const float var  = sq * (1.0f / 64.0f) - mean * mean;
    const float rstd = rsqrtf(var + 1e-5f) * 0.2f;   // * (1 - LAMBDA_INIT)

    float* op = OUT + (size_t)bh * S * D + (size_t)(q0 + qt * 16 + c) * D;
#pragma unroll
    for (int dt = 0; dt < 4; ++dt) {
      float4 o;
      o.x = (vals[dt * 4 + 0] - mean) * rstd;
      o.y = (vals[dt * 4 + 1] - mean) * rstd;
      o.z = (vals[dt * 4 + 2] - mean) * rstd;
      o.w = (vals[dt * 4 + 3] - mean) * rstd;
      *(float4*)(op + 16 * dt + 4 * g) = o;
    }
  }
}

extern "C" void kernel_launch(void* const* d_in, const int* in_sizes, int n_in,
                              void* d_out, int out_size, void* d_ws, size_t ws_size,
                              hipStream_t stream) {
  (void)in_sizes; (void)n_in; (void)out_size; (void)ws_size;
  const float* q  = (const float*)d_in[0];
  const float* k  = (const float*)d_in[1];
  const float* v  = (const float*)d_in[2];
  const float* lp = (const float*)d_in[3];
  float* out = (float*)d_out;

  __bf16* ks = (__bf16*)d_ws;                              // 8 MiB
  __bf16* vs = (__bf16*)((char*)d_ws + (8u << 20));        // 8 MiB

  kpack<<<dim3(2048), dim3(256), 0, stream>>>(k, ks);
  vpack<<<dim3(1024), dim3(256), 0, stream>>>(v, vs);
  diffattn<<<dim3(512), dim3(256), 0, stream>>>(q, ks, vs, lp, out);
}